// Round 3
// baseline (12332.375 us; speedup 1.0000x reference)
//
#include <hip/hip_runtime.h>

#define T_   256
#define B_   128
#define W_   1024
#define G_   4096
#define NWG  256
#define NTHR 512

typedef __bf16 bf16x8 __attribute__((ext_vector_type(8)));
typedef __bf16 bf16x4 __attribute__((ext_vector_type(4)));
typedef float  f32x4  __attribute__((ext_vector_type(4)));

// LDS layout (bytes): [0,131072) 4 weight slices (each 1024k x 16c bf16, k-contig per col, XOR-swizzled)
// Z tiles use stride 18 floats (not 17): row-group bank bases land on {0,8,16,24}
// -> every bank exactly 2-way across a wave = free (m136); 17 gave a 4-way hot spot.
#define ZSTRIDE   18
#define LDS_Z0    131072   // 128 x 18 f32 scratch for z0 tile (9216 B)
#define LDS_Z1    140288   // 128 x 18 f32 scratch for z1 tile (9216 B)
#define LDS_BIAS  149504   // 2 x 16 f32
#define LDS_TOTAL 149632

__device__ __forceinline__ float sigf(float x)   { return 1.f / (1.f + __expf(-x)); }
__device__ __forceinline__ float tanhf_(float x) { return 1.f - 2.f / (__expf(2.f * x) + 1.f); }

// resets dtype auto-detect: mode 0 = int32, 1 = uint8 (bool bytes), 2 = float32
__device__ __forceinline__ int read_reset(const void* r, int mode, int idx) {
  if (mode == 0) return ((const int*)r)[idx] != 0;
  if (mode == 1) return ((const unsigned char*)r)[idx] != 0;
  return ((const float*)r)[idx] != 0.0f;
}

// Sense-reversing grid barrier. Agent-scope atomics operate at the coherent
// point (valid cross-XCD); one release fence (wb L2) before arrival, one
// acquire fence (inv L1/L2) after exit — NOT per spin poll (per-poll inv
// would thrash the XCD's L2 and evict the phase working set). Generation
// bump is RELEASE so the count reset can never be overtaken by a
// next-barrier arrival (lost-increment deadlock otherwise).
__device__ __forceinline__ void grid_sync(unsigned* bar) {
  __syncthreads();                       // drains all 8 waves' stores to L2
  if (threadIdx.x == 0) {
    __builtin_amdgcn_fence(__ATOMIC_RELEASE, "agent");   // wb dirty L2 -> coherent pt
    unsigned g = __hip_atomic_load(bar + 1, __ATOMIC_RELAXED, __HIP_MEMORY_SCOPE_AGENT);
    unsigned a = __hip_atomic_fetch_add(bar, 1u, __ATOMIC_RELAXED, __HIP_MEMORY_SCOPE_AGENT);
    if (a == NWG - 1) {
      __hip_atomic_store(bar, 0u, __ATOMIC_RELAXED, __HIP_MEMORY_SCOPE_AGENT);
      __hip_atomic_fetch_add(bar + 1, 1u, __ATOMIC_RELEASE, __HIP_MEMORY_SCOPE_AGENT);
    } else {
      while (__hip_atomic_load(bar + 1, __ATOMIC_RELAXED, __HIP_MEMORY_SCOPE_AGENT) == g)
        __builtin_amdgcn_s_sleep(2);
    }
    __builtin_amdgcn_fence(__ATOMIC_ACQUIRE, "agent");   // inv stale L1/L2
  }
  __syncthreads();
}

// Persistent scanned-LSTM. 256 WGs x 512 thr (1 WG/CU, 149.6KB LDS). Each WG
// owns 4 hidden units/layer; all 4 weight column-slices (128KB bf16) live in
// LDS for the whole scan. Phase p computes layer0(step p) + layer1(step p-1)
// -> 1 grid barrier per step. Waves: 4 row-quads x 2 K-halves; each wave does
// 2 row-tiles x K/2 so each B-fragment ds_read is reused twice (LDS traffic
// 512KB/CU/phase). K-partials reduced in LDS (kh0 store, sync, kh1 add).
template <bool XBF16>
__global__ __launch_bounds__(NTHR, 2)
void lstm_scan(const float* __restrict__ xs, const void* __restrict__ rst,
               const float* __restrict__ Wx, const float* __restrict__ Wh,
               const float* __restrict__ bb, float* __restrict__ out,
               unsigned short* xsb_u, unsigned short* h0a_u, unsigned short* h0b_u,
               unsigned short* h1a_u, unsigned short* h1b_u, unsigned* bar) {
  extern __shared__ char smem[];
  __bf16* xsb = (__bf16*)xsb_u;
  __bf16* h0a = (__bf16*)h0a_u; __bf16* h0b = (__bf16*)h0b_u;
  __bf16* h1a = (__bf16*)h1a_u; __bf16* h1b = (__bf16*)h1b_u;
  const int tid = threadIdx.x;
  const int wg  = blockIdx.x;
  const int u0  = wg * 4;                    // this WG's first hidden unit (both layers)

  // ---------------- prepass ----------------
  // (a) resets dtype detection (WG 0 scans bit patterns; 8192 ints covers the
  //     whole buffer if uint8, first quarter if int32/f32 — ~1.6k resets seen)
  if (wg == 0) {
    const int* ri = (const int*)rst;
    unsigned f = 0;
    for (int i = tid; i < (T_ * B_) / 4; i += NTHR) {
      unsigned v = (unsigned)ri[i];
      if (v > 1u) f |= 1u;                       // not plain int32 0/1
      if (v != 0u && v != 0x3F800000u) f |= 2u;  // not float 0.0/1.0
    }
    if (f) atomicOr(bar + 2, f);
  }
  // (b) xs f32 -> bf16 (one-time; halves per-phase broadcast bytes)
  if (XBF16) {
    const int gt = wg * NTHR + tid;
    const f32x4* src = (const f32x4*)xs;
    bf16x4* dst = (bf16x4*)xsb;
    for (int i = gt; i < (T_ * B_ * W_) / 4; i += NWG * NTHR) {
      f32x4 v = src[i];
      bf16x4 o;
      o[0] = (__bf16)v[0]; o[1] = (__bf16)v[1]; o[2] = (__bf16)v[2]; o[3] = (__bf16)v[3];
      dst[i] = o;
    }
  }
  // (c) zero the 4 h double-buffers (contiguous 1 MiB; ws arrives poisoned)
  {
    const int gt = wg * NTHR + tid;
    uint4* hz = (uint4*)h0a;
    const uint4 z4 = {0u, 0u, 0u, 0u};
    for (int i = gt; i < 65536; i += NWG * NTHR) hz[i] = z4;
  }
  // (d) weight slices f32 -> bf16 -> LDS (per packed-col c: k-contiguous 2KB,
  //     byte ^= (c&7)<<4 swizzle), + bias
  {
    const int c  = tid & 15, kc = tid >> 4;          // c: packed col (gate*4+du)
    const int col0 = ((c >> 2) << 10) + u0 + (c & 3);
    const int sw = (c & 7) << 4;
    const float* srcs[4] = { Wx, Wh, Wx + (size_t)W_ * G_, Wh + (size_t)W_ * G_ };
    for (int m = 0; m < 4; ++m) {
      const float* s = srcs[m] + col0;
      char* base = smem + m * 32768 + c * 2048;
      for (int kk = 0; kk < 32; ++kk) {
        const int k = kc * 32 + kk;
        *(__bf16*)(base + ((k * 2) ^ sw)) = (__bf16)s[(size_t)k * G_];
      }
    }
    if (tid < 32) {
      const int cc = tid & 15, l = tid >> 4;
      const int col = ((cc >> 2) << 10) + u0 + (cc & 3);
      ((float*)(smem + LDS_BIAS))[l * 16 + cc] = bb[l * G_ + col];
    }
  }
  grid_sync(bar);
  const unsigned mf = *(volatile unsigned*)(bar + 2);
  const int rmode = ((mf & 1u) == 0) ? 0 : (((mf & 2u) == 0) ? 2 : 1);

  // wave decomposition: wv = rq (row quad, 32 batch rows) + kh (K half)
  const int lane = tid & 63, wv = tid >> 6;
  const int rq   = wv & 3;                   // rows rq*32 .. rq*32+31
  const int kh   = wv >> 2;                  // k in [kh*512, kh*512+512)
  const int lrow = lane & 15;
  const int kgrp = lane >> 4;                // k-group -> 8 consecutive k
  const int c16  = lane & 15;                // B column this lane supplies
  const int swz  = (c16 & 7) << 4;
  const char* wlds = smem + c16 * 2048;
  const int row0 = (rq << 5) + lrow;         // A row, tile rt=0
  const int row1 = row0 + 16;                // A row, tile rt=1
  const int gb = tid >> 2, du = tid & 3;     // gate-phase mapping: (batch, unit)

  float c0 = 0.f, c1 = 0.f;                  // register-resident cell state

  for (int p = 0; p <= T_; ++p) {
    const __bf16* h0r = (p & 1) ? h0a : h0b; // read parity (p-1)&1
    __bf16*       h0w = (p & 1) ? h0b : h0a; // write parity p&1
    const __bf16* h1r = (p & 1) ? h1a : h1b;
    __bf16*       h1w = (p & 1) ? h1b : h1a;
    const int tx = (p < T_) ? p : (T_ - 1);
    const int r0a = (p < T_) ? read_reset(rst, rmode, p * B_ + row0) : 0;
    const int r0b = (p < T_) ? read_reset(rst, rmode, p * B_ + row1) : 0;
    const int r1a = (p >= 1) ? read_reset(rst, rmode, (p - 1) * B_ + row0) : 0;
    const int r1b = (p >= 1) ? read_reset(rst, rmode, (p - 1) * B_ + row1) : 0;

    const __bf16* xq0 = xsb + (size_t)tx * (B_ * W_) + row0 * W_;
    const __bf16* xq1 = xsb + (size_t)tx * (B_ * W_) + row1 * W_;
    const float*  xf0 = xs  + (size_t)tx * (B_ * W_) + row0 * W_;
    const float*  xf1 = xs  + (size_t)tx * (B_ * W_) + row1 * W_;
    const __bf16* h0p0 = h0r + row0 * W_;
    const __bf16* h0p1 = h0r + row1 * W_;
    const __bf16* h1p0 = h1r + row0 * W_;
    const __bf16* h1p1 = h1r + row1 * W_;

    f32x4 a00 = {0.f,0.f,0.f,0.f}, a01 = {0.f,0.f,0.f,0.f};  // layer0 partials rt0/rt1
    f32x4 a10 = {0.f,0.f,0.f,0.f}, a11 = {0.f,0.f,0.f,0.f};  // layer1 partials rt0/rt1
    const bf16x8 z8 = {};

    #pragma unroll 2
    for (int ki = 0; ki < 16; ++ki) {
      const int kb   = (kh << 9) + (ki << 5);
      const int ko   = kb + (kgrp << 3);
      const int koff = ((kb << 1) + (kgrp << 4)) ^ swz;
      bf16x8 w0 = *(const bf16x8*)(wlds +     0 + koff);   // Wx0
      bf16x8 w1 = *(const bf16x8*)(wlds + 32768 + koff);   // Wh0
      bf16x8 w2 = *(const bf16x8*)(wlds + 65536 + koff);   // Wx1
      bf16x8 w3 = *(const bf16x8*)(wlds + 98304 + koff);   // Wh1

      bf16x8 ax0, ax1;
      if constexpr (XBF16) {
        ax0 = *(const bf16x8*)(xq0 + ko);
        ax1 = *(const bf16x8*)(xq1 + ko);
      } else {
        f32x4 xa = *(const f32x4*)(xf0 + ko), xb2 = *(const f32x4*)(xf0 + ko + 4);
        ax0[0]=(__bf16)xa[0];  ax0[1]=(__bf16)xa[1];  ax0[2]=(__bf16)xa[2];  ax0[3]=(__bf16)xa[3];
        ax0[4]=(__bf16)xb2[0]; ax0[5]=(__bf16)xb2[1]; ax0[6]=(__bf16)xb2[2]; ax0[7]=(__bf16)xb2[3];
        f32x4 ya = *(const f32x4*)(xf1 + ko), yb2 = *(const f32x4*)(xf1 + ko + 4);
        ax1[0]=(__bf16)ya[0];  ax1[1]=(__bf16)ya[1];  ax1[2]=(__bf16)ya[2];  ax1[3]=(__bf16)ya[3];
        ax1[4]=(__bf16)yb2[0]; ax1[5]=(__bf16)yb2[1]; ax1[6]=(__bf16)yb2[2]; ax1[7]=(__bf16)yb2[3];
      }
      bf16x8 g00 = *(const bf16x8*)(h0p0 + ko);
      bf16x8 g01 = *(const bf16x8*)(h0p1 + ko);
      bf16x8 g10 = *(const bf16x8*)(h1p0 + ko);
      bf16x8 g11 = *(const bf16x8*)(h1p1 + ko);

      // rt = 0 (rows rq*32 + 0..15)
      a00 = __builtin_amdgcn_mfma_f32_16x16x32_bf16(ax0, w0, a00, 0, 0, 0);
      a00 = __builtin_amdgcn_mfma_f32_16x16x32_bf16(r0a ? z8 : g00, w1, a00, 0, 0, 0);
      a10 = __builtin_amdgcn_mfma_f32_16x16x32_bf16(g00, w2, a10, 0, 0, 0);        // y unmasked
      a10 = __builtin_amdgcn_mfma_f32_16x16x32_bf16(r1a ? z8 : g10, w3, a10, 0, 0, 0);
      // rt = 1 (rows rq*32 + 16..31)
      a01 = __builtin_amdgcn_mfma_f32_16x16x32_bf16(ax1, w0, a01, 0, 0, 0);
      a01 = __builtin_amdgcn_mfma_f32_16x16x32_bf16(r0b ? z8 : g01, w1, a01, 0, 0, 0);
      a11 = __builtin_amdgcn_mfma_f32_16x16x32_bf16(g01, w2, a11, 0, 0, 0);
      a11 = __builtin_amdgcn_mfma_f32_16x16x32_bf16(r1b ? z8 : g11, w3, a11, 0, 0, 0);
    }

    // K-partial reduction in LDS. D layout: row=(lane>>4)*4+v, col=lane&15.
    {
      float* z0 = (float*)(smem + LDS_Z0);
      float* z1 = (float*)(smem + LDS_Z1);
      const int zr0 = (rq << 5) + (kgrp << 2);
      const int zr1 = zr0 + 16;
      if (kh == 0) {
        if (p < T_) {
          #pragma unroll
          for (int v = 0; v < 4; ++v) { z0[(zr0+v)*ZSTRIDE + c16] = a00[v]; z0[(zr1+v)*ZSTRIDE + c16] = a01[v]; }
        }
        if (p >= 1) {
          #pragma unroll
          for (int v = 0; v < 4; ++v) { z1[(zr0+v)*ZSTRIDE + c16] = a10[v]; z1[(zr1+v)*ZSTRIDE + c16] = a11[v]; }
        }
      }
      __syncthreads();
      if (kh == 1) {
        if (p < T_) {
          #pragma unroll
          for (int v = 0; v < 4; ++v) { z0[(zr0+v)*ZSTRIDE + c16] += a00[v]; z0[(zr1+v)*ZSTRIDE + c16] += a01[v]; }
        }
        if (p >= 1) {
          #pragma unroll
          for (int v = 0; v < 4; ++v) { z1[(zr0+v)*ZSTRIDE + c16] += a10[v]; z1[(zr1+v)*ZSTRIDE + c16] += a11[v]; }
        }
      }
      __syncthreads();
    }

    const float* bz = (const float*)(smem + LDS_BIAS);
    if (p < T_) {                               // gates, layer0, step p
      const float* z0 = (const float*)(smem + LDS_Z0);
      const float zi = z0[gb * ZSTRIDE + du]      + bz[du];
      const float zf = z0[gb * ZSTRIDE + 4 + du]  + bz[4 + du];
      const float zg = z0[gb * ZSTRIDE + 8 + du]  + bz[8 + du];
      const float zo = z0[gb * ZSTRIDE + 12 + du] + bz[12 + du];
      const float ii = sigf(zi), ff = sigf(zf), gg = tanhf_(zg), oo = sigf(zo);
      if (read_reset(rst, rmode, p * B_ + gb)) c0 = 0.f;
      c0 = ff * c0 + ii * gg;
      const float h = oo * tanhf_(c0);
      h0w[gb * W_ + u0 + du] = (__bf16)h;
    }
    if (p >= 1) {                               // gates, layer1, step p-1 (+ output)
      const float* z1 = (const float*)(smem + LDS_Z1);
      const float zi = z1[gb * ZSTRIDE + du]      + bz[16 + du];
      const float zf = z1[gb * ZSTRIDE + 4 + du]  + bz[20 + du];
      const float zg = z1[gb * ZSTRIDE + 8 + du]  + bz[24 + du];
      const float zo = z1[gb * ZSTRIDE + 12 + du] + bz[28 + du];
      const float ii = sigf(zi), ff = sigf(zf), gg = tanhf_(zg), oo = sigf(zo);
      if (read_reset(rst, rmode, (p - 1) * B_ + gb)) c1 = 0.f;
      c1 = ff * c1 + ii * gg;
      const float h = oo * tanhf_(c1);
      h1w[gb * W_ + u0 + du] = (__bf16)h;
      out[(size_t)(p - 1) * (B_ * W_) + gb * W_ + u0 + du] = h;
    }
    grid_sync(bar);
  }
}

extern "C" void kernel_launch(void* const* d_in, const int* in_sizes, int n_in,
                              void* d_out, int out_size, void* d_ws, size_t ws_size,
                              hipStream_t stream) {
  const float* xs  = (const float*)d_in[0];
  const void*  rst = (const void*)d_in[1];
  const float* Wx  = (const float*)d_in[2];
  const float* Wh  = (const float*)d_in[3];
  const float* bb  = (const float*)d_in[4];
  float* out = (float*)d_out;

  char* ws = (char*)d_ws;
  const size_t xsb_bytes = (size_t)T_ * B_ * W_ * 2;   // 64 MiB
  const size_t h_bytes   = (size_t)4 * B_ * W_ * 2;    // 1 MiB (4 contiguous buffers)
  const bool xb = ws_size >= xsb_bytes + h_bytes + 64;

  unsigned short* xsb = (unsigned short*)ws;
  char* hbase = xb ? (ws + xsb_bytes) : ws;
  unsigned short* h0a = (unsigned short*)hbase;
  unsigned short* h0b = h0a + B_ * W_;
  unsigned short* h1a = h0b + B_ * W_;
  unsigned short* h1b = h1a + B_ * W_;
  unsigned* bar = (unsigned*)(hbase + h_bytes);

  hipMemsetAsync(bar, 0, 64, stream);   // barrier count/gen + dtype flags

  void* args[] = { (void*)&xs, (void*)&rst, (void*)&Wx, (void*)&Wh, (void*)&bb, (void*)&out,
                   (void*)&xsb, (void*)&h0a, (void*)&h0b, (void*)&h1a, (void*)&h1b, (void*)&bar };

  if (xb) {
    hipFuncSetAttribute(reinterpret_cast<const void*>(&lstm_scan<true>),
                        hipFuncAttributeMaxDynamicSharedMemorySize, LDS_TOTAL);
    hipLaunchCooperativeKernel(reinterpret_cast<const void*>(&lstm_scan<true>),
                               dim3(NWG), dim3(NTHR), args, LDS_TOTAL, stream);
  } else {
    hipFuncSetAttribute(reinterpret_cast<const void*>(&lstm_scan<false>),
                        hipFuncAttributeMaxDynamicSharedMemorySize, LDS_TOTAL);
    hipLaunchCooperativeKernel(reinterpret_cast<const void*>(&lstm_scan<false>),
                               dim3(NWG), dim3(NTHR), args, LDS_TOTAL, stream);
  }
}

// Round 6
// 7012.637 us; speedup vs baseline: 1.7586x; 1.7586x over previous
//
#include <hip/hip_runtime.h>

#define T_   256
#define B_   128
#define W_   1024
#define G_   4096
#define NWG  256
#define NTHR 512

typedef __bf16 bf16x8 __attribute__((ext_vector_type(8)));
typedef __bf16 bf16x4 __attribute__((ext_vector_type(4)));
typedef float  f32x4  __attribute__((ext_vector_type(4)));
typedef unsigned int u32x2 __attribute__((ext_vector_type(2)));
typedef unsigned int u32x4 __attribute__((ext_vector_type(4)));

// LDS layout (bytes): [0,131072) 4 weight slices (each 1024k x 16c bf16, k-contig per col, XOR-swizzled)
#define ZSTRIDE   18
#define LDS_Z0    131072   // 128 x 18 f32 scratch for z0 tile
#define LDS_Z1    140288   // 128 x 18 f32 scratch for z1 tile
#define LDS_BIAS  149504   // 2 x 16 f32
#define LDS_TOTAL 149632

__device__ __forceinline__ float sigf(float x)   { return 1.f / (1.f + __expf(-x)); }
__device__ __forceinline__ float tanhf_(float x) { return 1.f - 2.f / (__expf(2.f * x) + 1.f); }

__device__ __forceinline__ int read_reset(const void* r, int mode, int idx) {
  if (mode == 0) return ((const int*)r)[idx] != 0;
  if (mode == 1) return ((const unsigned char*)r)[idx] != 0;
  return ((const float*)r)[idx] != 0.0f;
}

// ---- coherent (cross-XCD) memory ops: sc0 sc1 = through/beyond L2 ----
// NOTE: asm "v" operands must be scalars or ext-vectors (HIP uint4 is a struct
// -> "indirect register inputs" compile error; bit_cast payloads to u32xN).
#define GLD_C(dst, p) asm volatile("global_load_dwordx4 %0, %1, off sc0 sc1" : "=v"(dst) : "v"(p))
#define GLD_N(dst, p) asm volatile("global_load_dwordx4 %0, %1, off"         : "=v"(dst) : "v"(p))
#define WAITV(N) do { asm volatile("s_waitcnt vmcnt(" #N ")" ::: "memory"); \
                      __builtin_amdgcn_sched_barrier(0); } while (0)

// Tree grid barrier: 8 sub-counters (distinct 128B lines, 32 WGs each) -> root(8)
// -> monotone generation word. Relaxed atomics only; store-visibility comes from
// each thread's explicit s_waitcnt vmcnt(0) on its sc0sc1 stores BEFORE arrival.
// No buffer_wbl2 / buffer_inv anywhere (those were 32 L2 sweeps/XCD/phase in r3).
// bar words: [0]=root, [32]=gen, [64]=reset-dtype flags, [96+32i]=sub_i.
__device__ __forceinline__ void grid_sync(unsigned* bar, unsigned target, int wg) {
  __syncthreads();
  if (threadIdx.x == 0) {
    unsigned* sub = bar + 96 + (wg & 7) * 32;
    bool resetter = false;
    unsigned a = __hip_atomic_fetch_add(sub, 1u, __ATOMIC_RELAXED, __HIP_MEMORY_SCOPE_AGENT);
    if (a == 31) {
      unsigned ra = __hip_atomic_fetch_add(bar, 1u, __ATOMIC_RELAXED, __HIP_MEMORY_SCOPE_AGENT);
      if (ra == 7) {
        #pragma unroll
        for (int i = 0; i < 8; ++i)
          __hip_atomic_store(bar + 96 + i * 32, 0u, __ATOMIC_RELAXED, __HIP_MEMORY_SCOPE_AGENT);
        __hip_atomic_store(bar, 0u, __ATOMIC_RELAXED, __HIP_MEMORY_SCOPE_AGENT);
        asm volatile("s_waitcnt vmcnt(0)" ::: "memory");  // resets at L3 before gen bump
        __hip_atomic_store(bar + 32, target, __ATOMIC_RELAXED, __HIP_MEMORY_SCOPE_AGENT);
        resetter = true;
      }
    }
    if (!resetter) {
      while (__hip_atomic_load(bar + 32, __ATOMIC_RELAXED, __HIP_MEMORY_SCOPE_AGENT) < target)
        __builtin_amdgcn_s_sleep(2);
    }
  }
  __syncthreads();
}

// Persistent scanned-LSTM. 256 WGs x 512 thr (1 WG/CU, 149.6KB LDS). Weights
// resident in LDS; phase p = layer0(step p) + layer1(step p-1); 1 barrier/step.
// h state: sc0sc1 stores (write-through past L2) + sc0sc1 loads (bypass stale L2),
// software-pipelined depth-1 with counted vmcnt. x/resets normally cached.
template <bool XBF16>
__global__ __launch_bounds__(NTHR, 2)
void lstm_scan(const float* __restrict__ xs, const void* __restrict__ rst,
               const float* __restrict__ Wx, const float* __restrict__ Wh,
               const float* __restrict__ bb, float* __restrict__ out,
               unsigned short* xsb_u, unsigned short* h0a_u, unsigned short* h0b_u,
               unsigned short* h1a_u, unsigned short* h1b_u, unsigned* bar) {
  extern __shared__ char smem[];
  __bf16* xsb = (__bf16*)xsb_u;
  __bf16* h0a = (__bf16*)h0a_u; __bf16* h0b = (__bf16*)h0b_u;
  __bf16* h1a = (__bf16*)h1a_u; __bf16* h1b = (__bf16*)h1b_u;
  const int tid = threadIdx.x;
  const int wg  = blockIdx.x;
  const int u0  = wg * 4;

  // ---------------- prepass ----------------
  if (wg == 0) {   // (a) resets dtype detect
    const int* ri = (const int*)rst;
    unsigned f = 0;
    for (int i = tid; i < (T_ * B_) / 4; i += NTHR) {
      unsigned v = (unsigned)ri[i];
      if (v > 1u) f |= 1u;
      if (v != 0u && v != 0x3F800000u) f |= 2u;
    }
    if (f) atomicOr(bar + 64, f);
  }
  if (XBF16) {     // (b) xs f32 -> bf16, write-through (readers cache it cleanly)
    const int gt = wg * NTHR + tid;
    const f32x4* src = (const f32x4*)xs;
    for (int i = gt; i < (T_ * B_ * W_) / 4; i += NWG * NTHR) {
      f32x4 v = src[i];
      bf16x4 o;
      o[0] = (__bf16)v[0]; o[1] = (__bf16)v[1]; o[2] = (__bf16)v[2]; o[3] = (__bf16)v[3];
      u32x2 ov = __builtin_bit_cast(u32x2, o);
      asm volatile("global_store_dwordx2 %0, %1, off sc0 sc1" :: "v"((bf16x4*)xsb + i), "v"(ov) : "memory");
    }
  }
  {                // (c) zero h double-buffers, write-through
    const int gt = wg * NTHR + tid;
    const u32x4 z4 = {0u, 0u, 0u, 0u};
    for (int i = gt; i < 65536; i += NWG * NTHR)
      asm volatile("global_store_dwordx4 %0, %1, off sc0 sc1" :: "v"((u32x4*)h0a_u + i), "v"(z4) : "memory");
  }
  {                // (d) weight slices f32 -> bf16 -> LDS (XOR-swizzled) + bias
    const int c  = tid & 15, kc = tid >> 4;
    const int col0 = ((c >> 2) << 10) + u0 + (c & 3);
    const int sw = (c & 7) << 4;
    const float* srcs[4] = { Wx, Wh, Wx + (size_t)W_ * G_, Wh + (size_t)W_ * G_ };
    for (int m = 0; m < 4; ++m) {
      const float* s = srcs[m] + col0;
      char* base = smem + m * 32768 + c * 2048;
      for (int kk = 0; kk < 32; ++kk) {
        const int k = kc * 32 + kk;
        *(__bf16*)(base + ((k * 2) ^ sw)) = (__bf16)s[(size_t)k * G_];
      }
    }
    if (tid < 32) {
      const int cc = tid & 15, l = tid >> 4;
      const int col = ((cc >> 2) << 10) + u0 + (cc & 3);
      ((float*)(smem + LDS_BIAS))[l * 16 + cc] = bb[l * G_ + col];
    }
  }
  asm volatile("s_waitcnt vmcnt(0)" ::: "memory");   // drain own sc0sc1 stores
  grid_sync(bar, 1u, wg);
  const unsigned mf = __hip_atomic_load(bar + 64, __ATOMIC_RELAXED, __HIP_MEMORY_SCOPE_AGENT);
  const int rmode = ((mf & 1u) == 0) ? 0 : (((mf & 2u) == 0) ? 2 : 1);

  const int lane = tid & 63, wv = tid >> 6;
  const int rq   = wv & 3;
  const int kh   = wv >> 2;
  const int lrow = lane & 15;
  const int kgrp = lane >> 4;
  const int c16  = lane & 15;
  const int swz  = (c16 & 7) << 4;
  const char* wlds = smem + c16 * 2048;
  const int row0 = (rq << 5) + lrow;
  const int row1 = row0 + 16;
  const int gb = tid >> 2, du = tid & 3;
  const int ofs = (kh << 9) + (kgrp << 3);     // element offset of this lane's k-stream

  float c0 = 0.f, c1 = 0.f;

  for (int p = 0; p <= T_; ++p) {
    const __bf16* h0r = (p & 1) ? h0a : h0b;
    __bf16*       h0w = (p & 1) ? h0b : h0a;
    const __bf16* h1r = (p & 1) ? h1a : h1b;
    __bf16*       h1w = (p & 1) ? h1b : h1a;
    const int tx = (p < T_) ? p : (T_ - 1);
    int r0a = (p < T_) ? read_reset(rst, rmode, p * B_ + row0) : 0;
    int r0b = (p < T_) ? read_reset(rst, rmode, p * B_ + row1) : 0;
    int r1a = (p >= 1) ? read_reset(rst, rmode, (p - 1) * B_ + row0) : 0;
    int r1b = (p >= 1) ? read_reset(rst, rmode, (p - 1) * B_ + row1) : 0;

    const __bf16* pX0  = xsb + (size_t)tx * (B_ * W_) + row0 * W_ + ofs;
    const __bf16* pX1  = xsb + (size_t)tx * (B_ * W_) + row1 * W_ + ofs;
    const float*  pXf0 = xs  + (size_t)tx * (B_ * W_) + row0 * W_ + ofs;
    const float*  pXf1 = xs  + (size_t)tx * (B_ * W_) + row1 * W_ + ofs;
    const __bf16* pH00 = h0r + row0 * W_ + ofs;
    const __bf16* pH01 = h0r + row1 * W_ + ofs;
    const __bf16* pH10 = h1r + row0 * W_ + ofs;
    const __bf16* pH11 = h1r + row1 * W_ + ofs;

    f32x4 a00 = {0.f,0.f,0.f,0.f}, a01 = {0.f,0.f,0.f,0.f};
    f32x4 a10 = {0.f,0.f,0.f,0.f}, a11 = {0.f,0.f,0.f,0.f};
    const bf16x8 z8 = {};

    // pin reset values + clean vmcnt before the manually-counted region
    asm volatile("" :: "v"(r0a), "v"(r0b), "v"(r1a), "v"(r1b));
    asm volatile("s_waitcnt vmcnt(0)" ::: "memory");

    if constexpr (XBF16) {
      f32x4 Px0,Px1,P00,P01,P10,P11, Qx0,Qx1,Q00,Q01,Q10,Q11;
      GLD_N(Px0, pX0);  GLD_N(Px1, pX1);
      GLD_C(P00, pH00); GLD_C(P01, pH01); GLD_C(P10, pH10); GLD_C(P11, pH11);

#define KSTEP_B(CX0,CX1,C00,C01,C10,C11, NX0,NX1,N00,N01,N10,N11, KI, ISNEXT) \
      { \
        if (ISNEXT) { \
          const int no = ((KI) + 1) * 32; \
          GLD_N(NX0, pX0 + no);  GLD_N(NX1, pX1 + no); \
          GLD_C(N00, pH00 + no); GLD_C(N01, pH01 + no); \
          GLD_C(N10, pH10 + no); GLD_C(N11, pH11 + no); \
        } \
        const int koff = ((kh << 10) + ((KI) << 6) + (kgrp << 4)) ^ swz; \
        bf16x8 w0 = *(const bf16x8*)(wlds +     0 + koff); \
        bf16x8 w1 = *(const bf16x8*)(wlds + 32768 + koff); \
        bf16x8 w2 = *(const bf16x8*)(wlds + 65536 + koff); \
        bf16x8 w3 = *(const bf16x8*)(wlds + 98304 + koff); \
        if (ISNEXT) { WAITV(6); } else { WAITV(0); } \
        bf16x8 ax0 = __builtin_bit_cast(bf16x8, CX0); \
        bf16x8 ax1 = __builtin_bit_cast(bf16x8, CX1); \
        bf16x8 b00 = __builtin_bit_cast(bf16x8, C00); \
        bf16x8 b01 = __builtin_bit_cast(bf16x8, C01); \
        bf16x8 b10 = __builtin_bit_cast(bf16x8, C10); \
        bf16x8 b11 = __builtin_bit_cast(bf16x8, C11); \
        a00 = __builtin_amdgcn_mfma_f32_16x16x32_bf16(ax0, w0, a00, 0, 0, 0); \
        a00 = __builtin_amdgcn_mfma_f32_16x16x32_bf16(r0a ? z8 : b00, w1, a00, 0, 0, 0); \
        a10 = __builtin_amdgcn_mfma_f32_16x16x32_bf16(b00, w2, a10, 0, 0, 0); \
        a10 = __builtin_amdgcn_mfma_f32_16x16x32_bf16(r1a ? z8 : b10, w3, a10, 0, 0, 0); \
        a01 = __builtin_amdgcn_mfma_f32_16x16x32_bf16(ax1, w0, a01, 0, 0, 0); \
        a01 = __builtin_amdgcn_mfma_f32_16x16x32_bf16(r0b ? z8 : b01, w1, a01, 0, 0, 0); \
        a11 = __builtin_amdgcn_mfma_f32_16x16x32_bf16(b01, w2, a11, 0, 0, 0); \
        a11 = __builtin_amdgcn_mfma_f32_16x16x32_bf16(r1b ? z8 : b11, w3, a11, 0, 0, 0); \
      }

      #pragma unroll
      for (int kp = 0; kp < 8; ++kp) {
        KSTEP_B(Px0,Px1,P00,P01,P10,P11, Qx0,Qx1,Q00,Q01,Q10,Q11, 2*kp,   1);
        KSTEP_B(Qx0,Qx1,Q00,Q01,Q10,Q11, Px0,Px1,P00,P01,P10,P11, 2*kp+1, (kp < 7));
      }
#undef KSTEP_B
    } else {
      f32x4 Pxa0,Pxb0,Pxa1,Pxb1,P00,P01,P10,P11, Qxa0,Qxb0,Qxa1,Qxb1,Q00,Q01,Q10,Q11;
      GLD_N(Pxa0, pXf0); GLD_N(Pxb0, pXf0 + 4);
      GLD_N(Pxa1, pXf1); GLD_N(Pxb1, pXf1 + 4);
      GLD_C(P00, pH00);  GLD_C(P01, pH01); GLD_C(P10, pH10); GLD_C(P11, pH11);

#define KSTEP_F(CXA0,CXB0,CXA1,CXB1,C00,C01,C10,C11, NXA0,NXB0,NXA1,NXB1,N00,N01,N10,N11, KI, ISNEXT) \
      { \
        if (ISNEXT) { \
          const int no = ((KI) + 1) * 32; \
          GLD_N(NXA0, pXf0 + no); GLD_N(NXB0, pXf0 + no + 4); \
          GLD_N(NXA1, pXf1 + no); GLD_N(NXB1, pXf1 + no + 4); \
          GLD_C(N00, pH00 + no);  GLD_C(N01, pH01 + no); \
          GLD_C(N10, pH10 + no);  GLD_C(N11, pH11 + no); \
        } \
        const int koff = ((kh << 10) + ((KI) << 6) + (kgrp << 4)) ^ swz; \
        bf16x8 w0 = *(const bf16x8*)(wlds +     0 + koff); \
        bf16x8 w1 = *(const bf16x8*)(wlds + 32768 + koff); \
        bf16x8 w2 = *(const bf16x8*)(wlds + 65536 + koff); \
        bf16x8 w3 = *(const bf16x8*)(wlds + 98304 + koff); \
        if (ISNEXT) { WAITV(8); } else { WAITV(0); } \
        bf16x8 ax0, ax1; \
        _Pragma("unroll") \
        for (int j = 0; j < 4; ++j) { \
          ax0[j] = (__bf16)CXA0[j]; ax0[4+j] = (__bf16)CXB0[j]; \
          ax1[j] = (__bf16)CXA1[j]; ax1[4+j] = (__bf16)CXB1[j]; \
        } \
        bf16x8 b00 = __builtin_bit_cast(bf16x8, C00); \
        bf16x8 b01 = __builtin_bit_cast(bf16x8, C01); \
        bf16x8 b10 = __builtin_bit_cast(bf16x8, C10); \
        bf16x8 b11 = __builtin_bit_cast(bf16x8, C11); \
        a00 = __builtin_amdgcn_mfma_f32_16x16x32_bf16(ax0, w0, a00, 0, 0, 0); \
        a00 = __builtin_amdgcn_mfma_f32_16x16x32_bf16(r0a ? z8 : b00, w1, a00, 0, 0, 0); \
        a10 = __builtin_amdgcn_mfma_f32_16x16x32_bf16(b00, w2, a10, 0, 0, 0); \
        a10 = __builtin_amdgcn_mfma_f32_16x16x32_bf16(r1a ? z8 : b10, w3, a10, 0, 0, 0); \
        a01 = __builtin_amdgcn_mfma_f32_16x16x32_bf16(ax1, w0, a01, 0, 0, 0); \
        a01 = __builtin_amdgcn_mfma_f32_16x16x32_bf16(r0b ? z8 : b01, w1, a01, 0, 0, 0); \
        a11 = __builtin_amdgcn_mfma_f32_16x16x32_bf16(b01, w2, a11, 0, 0, 0); \
        a11 = __builtin_amdgcn_mfma_f32_16x16x32_bf16(r1b ? z8 : b11, w3, a11, 0, 0, 0); \
      }

      #pragma unroll
      for (int kp = 0; kp < 8; ++kp) {
        KSTEP_F(Pxa0,Pxb0,Pxa1,Pxb1,P00,P01,P10,P11, Qxa0,Qxb0,Qxa1,Qxb1,Q00,Q01,Q10,Q11, 2*kp,   1);
        KSTEP_F(Qxa0,Qxb0,Qxa1,Qxb1,Q00,Q01,Q10,Q11, Pxa0,Pxb0,Pxa1,Pxb1,P00,P01,P10,P11, 2*kp+1, (kp < 7));
      }
#undef KSTEP_F
    }

    // K-partial reduction in LDS (kh0 store, sync, kh1 add, sync)
    {
      float* z0 = (float*)(smem + LDS_Z0);
      float* z1 = (float*)(smem + LDS_Z1);
      const int zr0 = (rq << 5) + (kgrp << 2);
      const int zr1 = zr0 + 16;
      if (kh == 0) {
        if (p < T_) {
          #pragma unroll
          for (int v = 0; v < 4; ++v) { z0[(zr0+v)*ZSTRIDE + c16] = a00[v]; z0[(zr1+v)*ZSTRIDE + c16] = a01[v]; }
        }
        if (p >= 1) {
          #pragma unroll
          for (int v = 0; v < 4; ++v) { z1[(zr0+v)*ZSTRIDE + c16] = a10[v]; z1[(zr1+v)*ZSTRIDE + c16] = a11[v]; }
        }
      }
      __syncthreads();
      if (kh == 1) {
        if (p < T_) {
          #pragma unroll
          for (int v = 0; v < 4; ++v) { z0[(zr0+v)*ZSTRIDE + c16] += a00[v]; z0[(zr1+v)*ZSTRIDE + c16] += a01[v]; }
        }
        if (p >= 1) {
          #pragma unroll
          for (int v = 0; v < 4; ++v) { z1[(zr0+v)*ZSTRIDE + c16] += a10[v]; z1[(zr1+v)*ZSTRIDE + c16] += a11[v]; }
        }
      }
      __syncthreads();
    }

    const float* bz = (const float*)(smem + LDS_BIAS);
    if (p < T_) {
      const float* z0 = (const float*)(smem + LDS_Z0);
      const float zi = z0[gb * ZSTRIDE + du]      + bz[du];
      const float zf = z0[gb * ZSTRIDE + 4 + du]  + bz[4 + du];
      const float zg = z0[gb * ZSTRIDE + 8 + du]  + bz[8 + du];
      const float zo = z0[gb * ZSTRIDE + 12 + du] + bz[12 + du];
      const float ii = sigf(zi), ff = sigf(zf), gg = tanhf_(zg), oo = sigf(zo);
      if (read_reset(rst, rmode, p * B_ + gb)) c0 = 0.f;
      c0 = ff * c0 + ii * gg;
      const float h = oo * tanhf_(c0);
      unsigned hv = (unsigned)__builtin_bit_cast(unsigned short, (__bf16)h);
      asm volatile("global_store_short %0, %1, off sc0 sc1" :: "v"(h0w + gb * W_ + u0 + du), "v"(hv) : "memory");
    }
    if (p >= 1) {
      const float* z1 = (const float*)(smem + LDS_Z1);
      const float zi = z1[gb * ZSTRIDE + du]      + bz[16 + du];
      const float zf = z1[gb * ZSTRIDE + 4 + du]  + bz[20 + du];
      const float zg = z1[gb * ZSTRIDE + 8 + du]  + bz[24 + du];
      const float zo = z1[gb * ZSTRIDE + 12 + du] + bz[28 + du];
      const float ii = sigf(zi), ff = sigf(zf), gg = tanhf_(zg), oo = sigf(zo);
      if (read_reset(rst, rmode, (p - 1) * B_ + gb)) c1 = 0.f;
      c1 = ff * c1 + ii * gg;
      const float h = oo * tanhf_(c1);
      unsigned hv = (unsigned)__builtin_bit_cast(unsigned short, (__bf16)h);
      asm volatile("global_store_short %0, %1, off sc0 sc1" :: "v"(h1w + gb * W_ + u0 + du), "v"(hv) : "memory");
      out[(size_t)(p - 1) * (B_ * W_) + gb * W_ + u0 + du] = h;
    }
    asm volatile("s_waitcnt vmcnt(0)" ::: "memory");   // own h-stores visible pre-arrival
    grid_sync(bar, (unsigned)(p + 2), wg);
  }
}

extern "C" void kernel_launch(void* const* d_in, const int* in_sizes, int n_in,
                              void* d_out, int out_size, void* d_ws, size_t ws_size,
                              hipStream_t stream) {
  const float* xs  = (const float*)d_in[0];
  const void*  rst = (const void*)d_in[1];
  const float* Wx  = (const float*)d_in[2];
  const float* Wh  = (const float*)d_in[3];
  const float* bb  = (const float*)d_in[4];
  float* out = (float*)d_out;

  char* ws = (char*)d_ws;
  const size_t xsb_bytes = (size_t)T_ * B_ * W_ * 2;   // 64 MiB
  const size_t h_bytes   = (size_t)4 * B_ * W_ * 2;    // 1 MiB
  const bool xb = ws_size >= xsb_bytes + h_bytes + 2048;

  unsigned short* xsb = (unsigned short*)ws;
  char* hbase = xb ? (ws + xsb_bytes) : ws;
  unsigned short* h0a = (unsigned short*)hbase;
  unsigned short* h0b = h0a + B_ * W_;
  unsigned short* h1a = h0b + B_ * W_;
  unsigned short* h1b = h1a + B_ * W_;
  unsigned* bar = (unsigned*)(hbase + h_bytes);

  hipMemsetAsync(bar, 0, 2048, stream);

  void* args[] = { (void*)&xs, (void*)&rst, (void*)&Wx, (void*)&Wh, (void*)&bb, (void*)&out,
                   (void*)&xsb, (void*)&h0a, (void*)&h0b, (void*)&h1a, (void*)&h1b, (void*)&bar };

  if (xb) {
    (void)hipFuncSetAttribute(reinterpret_cast<const void*>(&lstm_scan<true>),
                              hipFuncAttributeMaxDynamicSharedMemorySize, LDS_TOTAL);
    (void)hipLaunchCooperativeKernel(reinterpret_cast<const void*>(&lstm_scan<true>),
                                     dim3(NWG), dim3(NTHR), args, LDS_TOTAL, stream);
  } else {
    (void)hipFuncSetAttribute(reinterpret_cast<const void*>(&lstm_scan<false>),
                              hipFuncAttributeMaxDynamicSharedMemorySize, LDS_TOTAL);
    (void)hipLaunchCooperativeKernel(reinterpret_cast<const void*>(&lstm_scan<false>),
                                     dim3(NWG), dim3(NTHR), args, LDS_TOTAL, stream);
  }
}